// Round 1
// baseline (930.426 us; speedup 1.0000x reference)
//
#include <hip/hip_runtime.h>
#include <math.h>

// Problem constants (from reference):
//   N = 500000 nodes, C = 256 channels, B = 1024 segments, hidden = C/R = 64
#define CCH   256
#define CCH4  64        // C / 4 (float4 groups per row)
#define BSEG  1024
#define HID   64

// ---------------------------------------------------------------------------
// Kernel 1: segment sum + max. batch is sorted, so segment `seg` occupies a
// contiguous row range [start, end) found by binary search. One block per
// segment, 4 waves; each wave processes rows strided by 4, with 64 lanes
// covering the 256 channels as float4 (one 1KB coalesced transaction/row).
// ---------------------------------------------------------------------------
__global__ __launch_bounds__(256) void seg_reduce_kernel(
    const float* __restrict__ x, const int* __restrict__ batch, int N,
    float* __restrict__ sum_res, float* __restrict__ max_res) {
  int seg = blockIdx.x;
  __shared__ int s_bounds[2];
  if (threadIdx.x < 2) {
    int tgt = seg + (int)threadIdx.x;  // lower_bound(batch, tgt)
    int lo = 0, hi = N;
    while (lo < hi) {
      int mid = (lo + hi) >> 1;
      if (batch[mid] < tgt) lo = mid + 1; else hi = mid;
    }
    s_bounds[threadIdx.x] = lo;
  }
  __syncthreads();
  int start = s_bounds[0], end = s_bounds[1];

  int wave = threadIdx.x >> 6;
  int lane = threadIdx.x & 63;
  const float4* x4 = (const float4*)x;

  float4 s = make_float4(0.f, 0.f, 0.f, 0.f);
  float4 m = make_float4(-INFINITY, -INFINITY, -INFINITY, -INFINITY);
  for (int r = start + wave; r < end; r += 4) {
    float4 v = x4[(size_t)r * CCH4 + lane];
    s.x += v.x; s.y += v.y; s.z += v.z; s.w += v.w;
    m.x = fmaxf(m.x, v.x); m.y = fmaxf(m.y, v.y);
    m.z = fmaxf(m.z, v.z); m.w = fmaxf(m.w, v.w);
  }

  __shared__ float4 sh_s[4][CCH4];
  __shared__ float4 sh_m[4][CCH4];
  sh_s[wave][lane] = s;
  sh_m[wave][lane] = m;
  __syncthreads();

  if (wave == 0) {
    float4 ts = sh_s[0][lane];
    float4 tm = sh_m[0][lane];
    for (int w = 1; w < 4; ++w) {
      float4 os = sh_s[w][lane];
      float4 om = sh_m[w][lane];
      ts.x += os.x; ts.y += os.y; ts.z += os.z; ts.w += os.w;
      tm.x = fmaxf(tm.x, om.x); tm.y = fmaxf(tm.y, om.y);
      tm.z = fmaxf(tm.z, om.z); tm.w = fmaxf(tm.w, om.w);
    }
    if (start == end) tm = make_float4(0.f, 0.f, 0.f, 0.f);  // empty segment -> 0 (torch_scatter fill)
    ((float4*)sum_res)[(size_t)seg * CCH4 + lane] = ts;
    ((float4*)max_res)[(size_t)seg * CCH4 + lane] = tm;
  }
}

// ---------------------------------------------------------------------------
// Kernel 2: y = relu(mlp(max_res) + mlp(sum_res)) per segment.
// mlp(h) = relu(h @ w1) @ w2; second matmul is linear, so
//   y[c] = relu( sum_j (hs[j] + hm[j]) * w2[j][c] ).
// One block (256 threads) per segment. Tiny: ~100 MFLOP total.
// ---------------------------------------------------------------------------
__global__ __launch_bounds__(256) void mlp_kernel(
    const float* __restrict__ sum_res, const float* __restrict__ max_res,
    const float* __restrict__ w1, const float* __restrict__ w2,
    float* __restrict__ y) {
  int seg = blockIdx.x;
  int t = threadIdx.x;
  __shared__ float srow[CCH];
  __shared__ float mrow[CCH];
  __shared__ float hsum[HID];
  __shared__ float hmax[HID];

  srow[t] = sum_res[(size_t)seg * CCH + t];
  mrow[t] = max_res[(size_t)seg * CCH + t];
  __syncthreads();

  if (t < HID) {
    float acc = 0.f;
    #pragma unroll 8
    for (int k = 0; k < CCH; ++k) acc = fmaf(srow[k], w1[k * HID + t], acc);
    hsum[t] = fmaxf(acc, 0.f);
  } else if (t < 2 * HID) {
    int j = t - HID;
    float acc = 0.f;
    #pragma unroll 8
    for (int k = 0; k < CCH; ++k) acc = fmaf(mrow[k], w1[k * HID + j], acc);
    hmax[j] = fmaxf(acc, 0.f);
  }
  __syncthreads();

  float acc = 0.f;
  #pragma unroll 8
  for (int j = 0; j < HID; ++j) acc = fmaf(hsum[j] + hmax[j], w2[j * CCH + t], acc);
  y[(size_t)seg * CCH + t] = fmaxf(acc, 0.f);
}

// ---------------------------------------------------------------------------
// Kernel 3: out[n][c] = x[n][c] * y[batch[n]][c], vectorized float4.
// N*C = 128M elements = 32M float4, exactly divisible. All 64 lanes of a
// wave share the same node n -> batch[n] is one scalar-cached load; y is
// 1 MB (L2-resident) read as coalesced 1KB rows.
// ---------------------------------------------------------------------------
__global__ __launch_bounds__(256) void gate_kernel(
    const float* __restrict__ x, const int* __restrict__ batch,
    const float* __restrict__ y, float* __restrict__ out, int total4) {
  int idx = blockIdx.x * blockDim.x + threadIdx.x;
  if (idx >= total4) return;
  int n = idx >> 6;        // node
  int q = idx & 63;        // float4 group within row
  int b = batch[n];
  const float4* x4 = (const float4*)x;
  const float4* y4 = (const float4*)y;
  float4 xv = x4[idx];
  float4 yv = y4[b * CCH4 + q];
  float4 o;
  o.x = xv.x * yv.x; o.y = xv.y * yv.y; o.z = xv.z * yv.z; o.w = xv.w * yv.w;
  ((float4*)out)[idx] = o;
}

extern "C" void kernel_launch(void* const* d_in, const int* in_sizes, int n_in,
                              void* d_out, int out_size, void* d_ws, size_t ws_size,
                              hipStream_t stream) {
  const float* x     = (const float*)d_in[0];   // [N, C]
  const int*   batch = (const int*)d_in[1];     // [N]
  const float* w1    = (const float*)d_in[2];   // [C, 64]
  const float* w2    = (const float*)d_in[3];   // [64, C]
  float* out = (float*)d_out;                   // [N, C]

  int N = in_sizes[1];                          // 500000

  // Workspace layout: sum_res [B*C] | max_res [B*C] | y [B*C]  (3 MB total)
  float* sum_res = (float*)d_ws;
  float* max_res = sum_res + (size_t)BSEG * CCH;
  float* y       = max_res + (size_t)BSEG * CCH;

  seg_reduce_kernel<<<BSEG, 256, 0, stream>>>(x, batch, N, sum_res, max_res);
  mlp_kernel<<<BSEG, 256, 0, stream>>>(sum_res, max_res, w1, w2, y);

  int total4 = N * CCH4;                        // N*C/4 = 32,000,000
  int blocks = (total4 + 255) / 256;
  gate_kernel<<<blocks, 256, 0, stream>>>(x, batch, y, out, total4);
}